// Round 2
// baseline (135.554 us; speedup 1.0000x reference)
//
#include <hip/hip_runtime.h>
#include <hip/hip_bf16.h>

typedef __attribute__((ext_vector_type(8))) __bf16 bf16x8;
typedef __attribute__((ext_vector_type(4))) float f32x4;

#define NB 16
#define CIN 32
#define COUT 64
#define HW 224
#define HP 226              // padded spatial
#define WS_X_OFF 65536      // bytes: wT at 0, padded NHWC X after

// ---- K1: weight OIHW fp32 -> wT[co][tap][cin] bf16 (64*9*32 = 18432) ----
__global__ void k_wxform(const float* __restrict__ w, unsigned short* __restrict__ wT) {
    int i = blockIdx.x * 256 + threadIdx.x;
    if (i >= COUT * 9 * CIN) return;
    int co = i / (9 * CIN);
    int r  = i % (9 * CIN);
    int tap = r / CIN;
    int c   = r % CIN;
    __hip_bfloat16 h = __float2bfloat16(w[(co * CIN + c) * 9 + tap]);
    wT[i] = __builtin_bit_cast(unsigned short, h);
}

// ---- K2: x NCHW fp32 -> X padded NHWC bf16 [16][226][226][32] ----
__global__ void k_xform(const float* __restrict__ x, unsigned short* __restrict__ X) {
    __shared__ unsigned short lds[HW * 40];   // [w][c] padded to 40 (16B-aligned rows)
    int bid = blockIdx.x;                     // 16*226
    int b = bid / HP, hp = bid % HP;
    int tid = threadIdx.x;
    unsigned long long rowbase = ((unsigned long long)(b * HP + hp)) * HP * CIN;
    if (hp >= 1 && hp <= HW) {
        int h = hp - 1;
        const float* xb = x + (unsigned long long)b * CIN * HW * HW + (unsigned long long)h * HW;
        for (int i = tid; i < CIN * HW; i += 256) {
            int c = i / HW, wc = i % HW;     // coalesced along w
            __hip_bfloat16 hv = __float2bfloat16(xb[(unsigned long long)c * HW * HW + wc]);
            lds[wc * 40 + c] = __builtin_bit_cast(unsigned short, hv);
        }
        __syncthreads();
        for (int i = tid; i < (HP * CIN) / 8; i += 256) {   // 904 x 16B stores
            int col = i >> 2, c0 = (i & 3) * 8;
            uint4 v = make_uint4(0, 0, 0, 0);
            if (col >= 1 && col <= HW)
                v = *reinterpret_cast<const uint4*>(&lds[(col - 1) * 40 + c0]);
            *reinterpret_cast<uint4*>(&X[rowbase + col * CIN + c0]) = v;
        }
    } else {                                  // top/bottom pad rows: zeros
        uint4 z = make_uint4(0, 0, 0, 0);
        for (int i = tid; i < (HP * CIN) / 8; i += 256)
            *reinterpret_cast<uint4*>(&X[rowbase + i * 8]) = z;
    }
}

// ---- K3: main MFMA conv. One block per (b,h); 4 waves, each 64px x 64cout ----
__global__ __launch_bounds__(256, 3)
void k_conv(const unsigned short* __restrict__ X, const unsigned short* __restrict__ wT,
            const float* __restrict__ bias, float* __restrict__ out) {
    int bid = blockIdx.x;
    int wg  = (bid & 7) * 448 + (bid >> 3);   // XCD-chunked swizzle, 3584 = 8*448
    int b = wg / HW, h = wg % HW;
    int wave = threadIdx.x >> 6, lane = threadIdx.x & 63;
    int lrow  = lane & 15;            // A-row (cout local), B-col (pixel local)
    int chunk = (lane >> 4) * 8;      // k sub-chunk (cin)
    const unsigned short* Xb = X + (unsigned long long)b * HP * HP * CIN;

    int pc[4];
    #pragma unroll
    for (int pf = 0; pf < 4; ++pf) {
        int px = wave * 64 + pf * 16 + lrow;
        pc[pf] = px < HW ? px : HW - 1;   // clamp masked tail (wave 3) into bounds
    }

    f32x4 acc[4][4];
    #pragma unroll
    for (int i = 0; i < 4; ++i)
        #pragma unroll
        for (int j = 0; j < 4; ++j) acc[i][j] = (f32x4){0.f, 0.f, 0.f, 0.f};

    #pragma unroll
    for (int dh = 0; dh < 3; ++dh) {
        const unsigned short* Xrow = Xb + (h + dh) * HP * CIN + chunk;
        #pragma unroll
        for (int dw = 0; dw < 3; ++dw) {
            int tap = dh * 3 + dw;
            bf16x8 wf[4], xf[4];
            #pragma unroll
            for (int cf = 0; cf < 4; ++cf)
                wf[cf] = *reinterpret_cast<const bf16x8*>(wT + (cf * 16 + lrow) * 288 + tap * 32 + chunk);
            #pragma unroll
            for (int pf = 0; pf < 4; ++pf)
                xf[pf] = *reinterpret_cast<const bf16x8*>(Xrow + (pc[pf] + dw) * CIN);
            #pragma unroll
            for (int cf = 0; cf < 4; ++cf)
                #pragma unroll
                for (int pf = 0; pf < 4; ++pf)
                    acc[cf][pf] = __builtin_amdgcn_mfma_f32_16x16x32_bf16(wf[cf], xf[pf], acc[cf][pf], 0, 0, 0);
        }
    }

    // epilogue: C/D layout col=lane&15 (pixel), row=(lane>>4)*4+reg (cout)
    #pragma unroll
    for (int cf = 0; cf < 4; ++cf) {
        float4 bv = *reinterpret_cast<const float4*>(bias + cf * 16 + (lane >> 4) * 4);
        const float* bvp = reinterpret_cast<const float*>(&bv);
        #pragma unroll
        for (int pf = 0; pf < 4; ++pf) {
            int pxb = wave * 64 + pf * 16;
            if (pxb < HW) {                  // 224 % 16 == 0: frag fully valid or fully masked
                int wc = pxb + lrow;
                #pragma unroll
                for (int r = 0; r < 4; ++r) {
                    int co = cf * 16 + (lane >> 4) * 4 + r;
                    out[((b * COUT + co) * HW + h) * HW + wc] = acc[cf][pf][r] + bvp[r];
                }
            }
        }
    }
}

// ---- fallback: naive direct fp32 conv (used only if ws too small) ----
__global__ void k_naive(const float* __restrict__ x, const float* __restrict__ w,
                        const float* __restrict__ bias, float* __restrict__ out, long long n) {
    long long i = (long long)blockIdx.x * 256 + threadIdx.x;
    if (i >= n) return;
    int wc = i % HW; long long t = i / HW;
    int h = t % HW; t /= HW;
    int co = t % COUT; int b = (int)(t / COUT);
    float s = bias[co];
    for (int c = 0; c < CIN; ++c)
        for (int dh = 0; dh < 3; ++dh) {
            int hy = h + dh - 1; if (hy < 0 || hy >= HW) continue;
            for (int dw = 0; dw < 3; ++dw) {
                int wx = wc + dw - 1; if (wx < 0 || wx >= HW) continue;
                s += x[(((long long)b * CIN + c) * HW + hy) * HW + wx] *
                     w[((co * CIN + c) * 3 + dh) * 3 + dw];
            }
        }
    out[i] = s;
}

extern "C" void kernel_launch(void* const* d_in, const int* in_sizes, int n_in,
                              void* d_out, int out_size, void* d_ws, size_t ws_size,
                              hipStream_t stream) {
    const float* x    = (const float*)d_in[0];
    const float* w    = (const float*)d_in[1];
    const float* bias = (const float*)d_in[2];
    float* out = (float*)d_out;

    size_t need = (size_t)WS_X_OFF + (size_t)NB * HP * HP * CIN * 2 + 4096;
    if (ws_size < need) {
        long long n = (long long)NB * COUT * HW * HW;
        k_naive<<<(int)((n + 255) / 256), 256, 0, stream>>>(x, w, bias, out, n);
        return;
    }
    unsigned short* wT = (unsigned short*)d_ws;
    unsigned short* X  = (unsigned short*)((char*)d_ws + WS_X_OFF);

    k_wxform<<<72, 256, 0, stream>>>(w, wT);
    k_xform<<<NB * HP, 256, 0, stream>>>(x, X);
    k_conv<<<NB * HW, 256, 0, stream>>>(X, wT, bias, out);
}

// Round 4
// 135.249 us; speedup vs baseline: 1.0023x; 1.0023x over previous
//
#include <hip/hip_runtime.h>
#include <hip/hip_bf16.h>

typedef __attribute__((ext_vector_type(8))) __bf16 bf16x8;
typedef __attribute__((ext_vector_type(4))) float f32x4;
typedef __attribute__((ext_vector_type(4))) unsigned int u32x4;
typedef unsigned long long ull;

#define NB 16
#define CIN 32
#define COUT 64
#define HW 224
#define HP 226              // padded spatial
#define WS_X_OFF 65536      // bytes: wT at 0, padded NHWC X after

__device__ __forceinline__ unsigned short f2bf(float f) {
    __hip_bfloat16 h = __float2bfloat16(f);
    return __builtin_bit_cast(unsigned short, h);
}

// ---- K1: weight OIHW fp32 -> wT[co][tap][cin] bf16 (64*9*32 = 18432) ----
__global__ void k_wxform(const float* __restrict__ w, unsigned short* __restrict__ wT) {
    int i = blockIdx.x * 256 + threadIdx.x;
    if (i >= COUT * 9 * CIN) return;
    int co = i / (9 * CIN);
    int r  = i % (9 * CIN);
    int tap = r / CIN;
    int c   = r % CIN;
    wT[i] = f2bf(w[(co * CIN + c) * 9 + tap]);
}

// ---- K2: x NCHW fp32 -> X padded NHWC bf16 [16][226][226][32], no LDS ----
// lane = output pixel; loop over c gives per-lane contiguous channel vector.
__global__ __launch_bounds__(256)
void k_xform(const float* __restrict__ x, unsigned short* __restrict__ X) {
    int bid = blockIdx.x;                     // 16*226
    int b = bid / HP, hp = bid % HP;
    ull rowbase = (ull)(b * HP + hp) * (HP * CIN);
    u32x4 z = (u32x4){0u, 0u, 0u, 0u};
    if (hp >= 1 && hp <= HW) {
        int h = hp - 1;
        int wc = threadIdx.x;                 // 0..255
        if (wc < HW) {
            const float* xb = x + (ull)b * CIN * HW * HW + (ull)h * HW + wc;
            unsigned int packed[16];
            #pragma unroll
            for (int c2 = 0; c2 < 16; ++c2) {
                float f0 = __builtin_nontemporal_load(xb + (ull)(2 * c2) * (HW * HW));
                float f1 = __builtin_nontemporal_load(xb + (ull)(2 * c2 + 1) * (HW * HW));
                packed[c2] = (unsigned int)f2bf(f0) | ((unsigned int)f2bf(f1) << 16);
            }
            unsigned short* dst = X + rowbase + (ull)(1 + wc) * CIN;
            #pragma unroll
            for (int k = 0; k < 4; ++k) {
                u32x4 v = (u32x4){packed[4 * k], packed[4 * k + 1],
                                  packed[4 * k + 2], packed[4 * k + 3]};
                *reinterpret_cast<u32x4*>(dst + k * 8) = v;
            }
        } else {
            int t = wc - HW;                  // 0..31 idle lanes: write w-pad columns
            if (t < 8) {
                ull off = (t < 4) ? (ull)t * 8 : (ull)(HP - 1) * CIN + (ull)(t - 4) * 8;
                *reinterpret_cast<u32x4*>(X + rowbase + off) = z;
            }
        }
    } else {                                  // top/bottom pad rows: zeros
        for (int i = threadIdx.x; i < (HP * CIN) / 8; i += 256)
            *reinterpret_cast<u32x4*>(X + rowbase + (ull)i * 8) = z;
    }
}

// ---- K3: main MFMA conv. One block per (b,h); 4 waves, each 64px x 64cout ----
// mfma(A=xf pixels, B=wf couts) -> D row=pixel,col=cout -> f32x4 stores along w.
__global__ __launch_bounds__(256, 3)
void k_conv(const unsigned short* __restrict__ X, const unsigned short* __restrict__ wT,
            const float* __restrict__ bias, float* __restrict__ out) {
    int bid = blockIdx.x;
    int wg  = (bid & 7) * 448 + (bid >> 3);   // XCD-chunked swizzle, 3584 = 8*448
    int b = wg / HW, h = wg % HW;
    int wave = threadIdx.x >> 6, lane = threadIdx.x & 63;
    int lrow  = lane & 15;            // A-row (pixel local) / B-col (cout local)
    int chunk = (lane >> 4) * 8;      // k sub-chunk (cin)
    const unsigned short* Xb = X + (ull)b * HP * HP * CIN;

    int pc[4];
    #pragma unroll
    for (int pf = 0; pf < 4; ++pf) {
        int px = wave * 64 + pf * 16 + lrow;
        pc[pf] = px < HW ? px : HW - 1;   // clamp masked tail (wave 3) into bounds
    }

    f32x4 acc[4][4];
    #pragma unroll
    for (int i = 0; i < 4; ++i)
        #pragma unroll
        for (int j = 0; j < 4; ++j) acc[i][j] = (f32x4){0.f, 0.f, 0.f, 0.f};

    #pragma unroll
    for (int dh = 0; dh < 3; ++dh) {
        const unsigned short* Xrow = Xb + (h + dh) * HP * CIN + chunk;
        #pragma unroll
        for (int dw = 0; dw < 3; ++dw) {
            int tap = dh * 3 + dw;
            bf16x8 wf[4], xf[4];
            #pragma unroll
            for (int cf = 0; cf < 4; ++cf)
                wf[cf] = *reinterpret_cast<const bf16x8*>(wT + (cf * 16 + lrow) * 288 + tap * 32 + chunk);
            #pragma unroll
            for (int pf = 0; pf < 4; ++pf)
                xf[pf] = *reinterpret_cast<const bf16x8*>(Xrow + (pc[pf] + dw) * CIN);
            #pragma unroll
            for (int cf = 0; cf < 4; ++cf)
                #pragma unroll
                for (int pf = 0; pf < 4; ++pf)
                    acc[cf][pf] = __builtin_amdgcn_mfma_f32_16x16x32_bf16(xf[pf], wf[cf], acc[cf][pf], 0, 0, 0);
        }
    }

    // epilogue: D row = pixel = (lane>>4)*4+reg, col = cout = lane&15
    #pragma unroll
    for (int cf = 0; cf < 4; ++cf) {
        int co = cf * 16 + lrow;
        float bv = bias[co];
        float* orow = out + ((ull)(b * COUT + co) * HW + h) * HW;
        #pragma unroll
        for (int pf = 0; pf < 4; ++pf) {
            int pxb = wave * 64 + pf * 16;
            if (pxb < HW) {                  // frag fully valid or fully masked
                int px0 = pxb + (lane >> 4) * 4;
                f32x4 v = acc[cf][pf] + bv;  // vector + scalar broadcast
                __builtin_nontemporal_store(v, reinterpret_cast<f32x4*>(orow + px0));
            }
        }
    }
}

// ---- fallback: naive direct fp32 conv (used only if ws too small) ----
__global__ void k_naive(const float* __restrict__ x, const float* __restrict__ w,
                        const float* __restrict__ bias, float* __restrict__ out, long long n) {
    long long i = (long long)blockIdx.x * 256 + threadIdx.x;
    if (i >= n) return;
    int wc = i % HW; long long t = i / HW;
    int h = t % HW; t /= HW;
    int co = t % COUT; int b = (int)(t / COUT);
    float s = bias[co];
    for (int c = 0; c < CIN; ++c)
        for (int dh = 0; dh < 3; ++dh) {
            int hy = h + dh - 1; if (hy < 0 || hy >= HW) continue;
            for (int dw = 0; dw < 3; ++dw) {
                int wx = wc + dw - 1; if (wx < 0 || wx >= HW) continue;
                s += x[(((long long)b * CIN + c) * HW + hy) * HW + wx] *
                     w[((co * CIN + c) * 3 + dh) * 3 + dw];
            }
        }
    out[i] = s;
}

extern "C" void kernel_launch(void* const* d_in, const int* in_sizes, int n_in,
                              void* d_out, int out_size, void* d_ws, size_t ws_size,
                              hipStream_t stream) {
    const float* x    = (const float*)d_in[0];
    const float* w    = (const float*)d_in[1];
    const float* bias = (const float*)d_in[2];
    float* out = (float*)d_out;

    size_t need = (size_t)WS_X_OFF + (size_t)NB * HP * HP * CIN * 2 + 4096;
    if (ws_size < need) {
        long long n = (long long)NB * COUT * HW * HW;
        k_naive<<<(int)((n + 255) / 256), 256, 0, stream>>>(x, w, bias, out, n);
        return;
    }
    unsigned short* wT = (unsigned short*)d_ws;
    unsigned short* X  = (unsigned short*)((char*)d_ws + WS_X_OFF);

    k_wxform<<<72, 256, 0, stream>>>(w, wT);
    k_xform<<<NB * HP, 256, 0, stream>>>(x, X);
    k_conv<<<NB * HW, 256, 0, stream>>>(X, wT, bias, out);
}

// Round 5
// 120.870 us; speedup vs baseline: 1.1215x; 1.1190x over previous
//
#include <hip/hip_runtime.h>
#include <hip/hip_bf16.h>

typedef __attribute__((ext_vector_type(8))) __bf16 bf16x8;
typedef __attribute__((ext_vector_type(4))) float f32x4;
typedef __attribute__((ext_vector_type(4))) unsigned int u32x4;
typedef unsigned long long ull;

#define NB 16
#define CIN 32
#define COUT 64
#define HW 224
#define HWHW (HW * HW)          // 50176
#define CHW (CIN * HW * HW)     // 1605632

__device__ __forceinline__ unsigned short f2bf(float f) {
    __hip_bfloat16 h = __float2bfloat16(f);
    return __builtin_bit_cast(unsigned short, h);
}

// ---- K1: weight OIHW fp32 -> wT[co][tap][cin] bf16 (64*9*32 = 18432) ----
__global__ void k_wxform(const float* __restrict__ w, unsigned short* __restrict__ wT) {
    int i = blockIdx.x * 256 + threadIdx.x;
    if (i >= COUT * 9 * CIN) return;
    int co = i / (9 * CIN);
    int r  = i % (9 * CIN);
    int tap = r / CIN;
    int c   = r % CIN;
    wT[i] = f2bf(w[(co * CIN + c) * 9 + tap]);
}

// ---- K2: fused conv. One block per (b,h); 4 waves, each 64px x 64cout. ----
// Reads NCHW fp32 directly, converts bf16 in-register, MFMA, dense f32x4 out.
__global__ __launch_bounds__(256, 3)
void k_fused(const float* __restrict__ x, const unsigned short* __restrict__ wT,
             const float* __restrict__ bias, float* __restrict__ out) {
    int bid = blockIdx.x;
    int wg  = (bid & 7) * 448 + (bid >> 3);   // XCD-chunked swizzle, 3584 = 8*448
    int b = wg / HW, h = wg % HW;
    int wave = threadIdx.x >> 6, lane = threadIdx.x & 63;
    int r = lane & 15;                // A-row (pixel local) / B-col (cout local)
    int q = lane >> 4;
    int chunk = q * 8;                // k sub-chunk (cin)
    const float* xb = x + (ull)b * CHW + (ull)chunk * HWHW;

    int pc[4];
    #pragma unroll
    for (int pf = 0; pf < 4; ++pf) {
        int px = wave * 64 + pf * 16 + r;
        pc[pf] = px < HW ? px : HW - 1;   // clamp masked tail (wave 3) into bounds
    }

    f32x4 acc[4][4];
    #pragma unroll
    for (int i = 0; i < 4; ++i)
        #pragma unroll
        for (int j = 0; j < 4; ++j) acc[i][j] = (f32x4){0.f, 0.f, 0.f, 0.f};

    #pragma unroll
    for (int dh = 0; dh < 3; ++dh) {
        int hy = h + dh - 1;
        if (hy >= 0 && hy < HW) {         // block-uniform branch (h-pad)
            const float* xrow = xb + (ull)hy * HW;
            #pragma unroll
            for (int dw = 0; dw < 3; ++dw) {
                int tap = dh * 3 + dw;
                bf16x8 wf[4];
                #pragma unroll
                for (int cf = 0; cf < 4; ++cf)
                    wf[cf] = *reinterpret_cast<const bf16x8*>(wT + (cf * 16 + r) * 288 + tap * 32 + chunk);
                bf16x8 xf[4];
                #pragma unroll
                for (int pf = 0; pf < 4; ++pf) {
                    int wx = pc[pf] + dw - 1;
                    bool valid = ((unsigned)wx < (unsigned)HW);   // w-pad -> zero
                    int wxc = valid ? wx : 0;
                    const float* p = xrow + wxc;
                    unsigned int pk0, pk1, pk2, pk3;
                    {
                        float f0 = p[0 * HWHW], f1 = p[1 * HWHW];
                        float f2 = p[2 * HWHW], f3 = p[3 * HWHW];
                        float f4 = p[4 * HWHW], f5 = p[5 * HWHW];
                        float f6 = p[6 * HWHW], f7 = p[7 * HWHW];
                        pk0 = (unsigned)f2bf(f0) | ((unsigned)f2bf(f1) << 16);
                        pk1 = (unsigned)f2bf(f2) | ((unsigned)f2bf(f3) << 16);
                        pk2 = (unsigned)f2bf(f4) | ((unsigned)f2bf(f5) << 16);
                        pk3 = (unsigned)f2bf(f6) | ((unsigned)f2bf(f7) << 16);
                    }
                    unsigned int zmask = valid ? 0xFFFFFFFFu : 0u;
                    u32x4 t = (u32x4){pk0 & zmask, pk1 & zmask, pk2 & zmask, pk3 & zmask};
                    xf[pf] = __builtin_bit_cast(bf16x8, t);
                }
                #pragma unroll
                for (int cf = 0; cf < 4; ++cf)
                    #pragma unroll
                    for (int pf = 0; pf < 4; ++pf)
                        acc[cf][pf] = __builtin_amdgcn_mfma_f32_16x16x32_bf16(xf[pf], wf[cf], acc[cf][pf], 0, 0, 0);
            }
        }
    }

    // epilogue: D row = pixel = (lane>>4)*4+reg, col = cout = lane&15
    // per instr: 16 lanes of a co-group fill full 64B lines -> dense stores.
    #pragma unroll
    for (int cf = 0; cf < 4; ++cf) {
        int co = cf * 16 + r;
        float bv = bias[co];
        float* orow = out + ((ull)(b * COUT + co) * HW + h) * HW;
        #pragma unroll
        for (int pf = 0; pf < 4; ++pf) {
            int pxb = wave * 64 + pf * 16;
            if (pxb < HW) {                  // frag fully valid or fully masked
                int px0 = pxb + q * 4;
                f32x4 v = acc[cf][pf] + bv;  // vector + scalar broadcast
                __builtin_nontemporal_store(v, reinterpret_cast<f32x4*>(orow + px0));
            }
        }
    }
}

// ---- fallback: naive direct fp32 conv (used only if ws too small) ----
__global__ void k_naive(const float* __restrict__ x, const float* __restrict__ w,
                        const float* __restrict__ bias, float* __restrict__ out, long long n) {
    long long i = (long long)blockIdx.x * 256 + threadIdx.x;
    if (i >= n) return;
    int wc = i % HW; long long t = i / HW;
    int h = t % HW; t /= HW;
    int co = t % COUT; int b = (int)(t / COUT);
    float s = bias[co];
    for (int c = 0; c < CIN; ++c)
        for (int dh = 0; dh < 3; ++dh) {
            int hy = h + dh - 1; if (hy < 0 || hy >= HW) continue;
            for (int dw = 0; dw < 3; ++dw) {
                int wx = wc + dw - 1; if (wx < 0 || wx >= HW) continue;
                s += x[(((long long)b * CIN + c) * HW + hy) * HW + wx] *
                     w[((co * CIN + c) * 3 + dh) * 3 + dw];
            }
        }
    out[i] = s;
}

extern "C" void kernel_launch(void* const* d_in, const int* in_sizes, int n_in,
                              void* d_out, int out_size, void* d_ws, size_t ws_size,
                              hipStream_t stream) {
    const float* x    = (const float*)d_in[0];
    const float* w    = (const float*)d_in[1];
    const float* bias = (const float*)d_in[2];
    float* out = (float*)d_out;

    if (ws_size < (size_t)(COUT * 9 * CIN * 2 + 1024)) {
        long long n = (long long)NB * COUT * HW * HW;
        k_naive<<<(int)((n + 255) / 256), 256, 0, stream>>>(x, w, bias, out, n);
        return;
    }
    unsigned short* wT = (unsigned short*)d_ws;

    k_wxform<<<72, 256, 0, stream>>>(w, wT);
    k_fused<<<NB * HW, 256, 0, stream>>>(x, wT, bias, out);
}